// Round 7
// baseline (52.023 us; speedup 1.0000x reference)
//
#include <hip/hip_runtime.h>
#include <hip/hip_bf16.h>

#define T_LEN 2048
#define NCOMP 8
#define HID 64
#define OUT_DIM 64
#define BATCH 64
#define MAX_EVENTS (T_LEN * NCOMP)
#define NCHUNK 32              // 2048 / 64-bit chunks per channel
#define NWAVE 16               // 1024-thread blocks

typedef unsigned long long u64;

// ---------------------------------------------------------------------------
// Single fused kernel: one block per batch item b (64 blocks x 1024 threads).
// Everything block-local => no cross-block fences/tickets (R4 lesson) and no
// second launch (R6 lesson: ~6-8us per graph node dominated the time).
// Phases:
//   1. coalesced load of x[b] + ballot -> bitmasks for all 8 channels
//   2. transition masks + per-channel suffix-min of first-transition
//   3. per channel c: nibble decode -> compact float4 {s,t,nxt} event list
//      -> 16-wave accumulate (5 VALU/event), accumulators carried across c
//   4. wave-0 head MLP, block-local
// Barrier structure per round: 2 syncthreads (see analysis: round r+1's
// wtot/elist writes are ordered after round r's reads by the barriers).
// ---------------------------------------------------------------------------
__global__ __launch_bounds__(1024) void fused_kernel(
    const float* __restrict__ x,     // [B, T, C]
    const float* __restrict__ W1,    // [11, 64]
    const float* __restrict__ b1,    // [64]
    const float* __restrict__ W2,    // [64, 64]
    const float* __restrict__ b2,    // [64]
    const float* __restrict__ P1,    // [65, 64]
    const float* __restrict__ pb1,   // [64]
    const float* __restrict__ P2,    // [64, 64]
    const float* __restrict__ pb2,   // [64]
    float* __restrict__ out)         // [64, 64]
{
    const int b    = blockIdx.x;
    const int tid  = threadIdx.x;
    const int lane = tid & 63;
    const int wave = tid >> 6;

    __shared__ u64 wsh[NCOMP][NCHUNK];       // raw bits
    __shared__ u64 tsh[NCOMP][NCHUNK];       // transition (run-start) masks
    __shared__ int nxtf[NCOMP][NCHUNK + 1];  // first transition in chunks >= k
    __shared__ int wtot[NWAVE];
    __shared__ float4 elist[T_LEN];          // compact events {s, t, nxt, 0}
    __shared__ float Sp[NWAVE][HID];
    __shared__ float sb[HID];
    __shared__ float zz[HID + 1];
    __shared__ float yy[HID];

    // --- Phase 1: coalesced load + ballot all channels ---
    const float4* xp = (const float4*)(x + (size_t)b * T_LEN * NCOMP);
    #pragma unroll
    for (int i = 0; i < 2; ++i) {
        int t = i * 1024 + tid;                  // chunk = i*16 + wave
        float4 v0 = xp[t * 2];
        float4 v1 = xp[t * 2 + 1];
        unsigned m = 0;
        m |= (v0.x > 0.5f) ? 1u   : 0u;
        m |= (v0.y > 0.5f) ? 2u   : 0u;
        m |= (v0.z > 0.5f) ? 4u   : 0u;
        m |= (v0.w > 0.5f) ? 8u   : 0u;
        m |= (v1.x > 0.5f) ? 16u  : 0u;
        m |= (v1.y > 0.5f) ? 32u  : 0u;
        m |= (v1.z > 0.5f) ? 64u  : 0u;
        m |= (v1.w > 0.5f) ? 128u : 0u;
        u64 mine = 0;
        #pragma unroll
        for (int c = 0; c < NCOMP; ++c) {
            u64 wd = __ballot((m >> c) & 1u);
            if (lane == c) mine = wd;
        }
        if (lane < NCOMP) wsh[lane][i * 16 + wave] = mine;
    }
    __syncthreads();

    // --- Phase 2: transition masks + suffix-min (channel = 32-lane subgroup) ---
    if (tid < NCOMP * NCHUNK) {                  // 256 threads
        const int c = tid >> 5;
        const int k = tid & 31;
        u64 w = wsh[c][k];
        u64 carry = k ? (wsh[c][k - 1] >> 63) : 0ULL;
        u64 tr = w ^ ((w << 1) | carry);
        if (k == 0) tr |= 1ULL;                  // t=0 always a start
        tsh[c][k] = tr;
        int first = tr ? k * 64 + (__ffsll((long long)tr) - 1) : T_LEN;
        #pragma unroll
        for (int off = 1; off < NCHUNK; off <<= 1) {
            int v = __shfl_down(first, off);     // stays in 32-lane subgroup
            if (k + off < NCHUNK) first = (v < first) ? v : first;
        }
        nxtf[c][k] = first;
        if (k == 0) nxtf[c][NCHUNK] = T_LEN;
    }
    __syncthreads();

    // --- Phase 3: per-channel rounds ---
    const float r8    = W1[8 * HID + lane];
    const float r9p   = W1[9 * HID + lane] * (1.0f / 2047.0f);
    const float r10p  = W1[10 * HID + lane] * (1.0f / 2048.0f);
    const float r9m   = r9p - r10p;              // coeff of t
    const float b1l   = b1[lane];

    float S0 = 0.0f, S1 = 0.0f, S2 = 0.0f, S3 = 0.0f;
    int totE = 0;                                // wave-uniform across block

    for (int c = 0; c < NCOMP; ++c) {
        // decode: 512 threads, one nibble each
        int nt = 0;
        unsigned tr4 = 0;
        u64 full = 0, wbits = 0;
        int ch = 0, sh = 0;
        if (tid < 512) {
            ch = tid >> 4;
            sh = (tid & 15) * 4;
            full  = tsh[c][ch];
            wbits = wsh[c][ch];
            tr4 = (unsigned)((full >> sh) & 0xFu);
            nt = __popc(tr4);
        }
        int incl = nt;
        #pragma unroll
        for (int o = 1; o < 64; o <<= 1) {
            int v = __shfl_up(incl, o);
            if (lane >= o) incl += v;
        }
        if (lane == 63) wtot[wave] = incl;
        __syncthreads();                          // barrier 1

        int waveoff = 0;
        for (int w = 0; w < wave; ++w) waveoff += wtot[w];
        int nE = 0;
        #pragma unroll
        for (int w = 0; w < NWAVE; ++w) nE += wtot[w];
        int off = waveoff + incl - nt;

        unsigned rem = tr4;
        while (rem) {
            int p = __ffs(rem) - 1;
            rem &= rem - 1;
            int t = (tid << 2) + p;
            unsigned s = (unsigned)((wbits >> (sh + p)) & 1ULL);
            int nxt;
            if (rem) {
                nxt = (tid << 2) + __ffs(rem) - 1;
            } else {
                int bp = sh + 4;
                u64 above = (bp >= 64) ? 0ULL : (full & (~0ULL << bp));
                nxt = above ? ch * 64 + (__ffsll((long long)above) - 1)
                            : nxtf[c][ch + 1];
            }
            float4 ev;
            ev.x = (float)s;
            ev.y = (float)t;
            ev.z = (float)nxt;
            ev.w = 0.0f;
            elist[off++] = ev;
        }
        __syncthreads();                          // barrier 2

        // accumulate: contiguous 16th per wave, 4-unrolled
        const float base0 = W1[c * HID + lane] + b1l;
        const int span = ((nE + 63) >> 6) << 2;   // ceil(nE/16) to mult of 4
        const int i0 = wave * span;
        const int i1 = (i0 + span < nE) ? (i0 + span) : nE;

        int i = i0;
        for (; i + 3 < i1; i += 4) {
            float4 e0 = elist[i];
            float4 e1 = elist[i + 1];
            float4 e2 = elist[i + 2];
            float4 e3 = elist[i + 3];
            float a0 = fmaf(e0.x, r8, base0);
            float a1 = fmaf(e1.x, r8, base0);
            float a2 = fmaf(e2.x, r8, base0);
            float a3 = fmaf(e3.x, r8, base0);
            a0 = fmaf(e0.z, r10p, a0);
            a1 = fmaf(e1.z, r10p, a1);
            a2 = fmaf(e2.z, r10p, a2);
            a3 = fmaf(e3.z, r10p, a3);
            a0 = fmaf(e0.y, r9m, a0);
            a1 = fmaf(e1.y, r9m, a1);
            a2 = fmaf(e2.y, r9m, a2);
            a3 = fmaf(e3.y, r9m, a3);
            S0 += fmaxf(a0, 0.0f);
            S1 += fmaxf(a1, 0.0f);
            S2 += fmaxf(a2, 0.0f);
            S3 += fmaxf(a3, 0.0f);
        }
        for (; i < i1; ++i) {
            float4 e = elist[i];
            float a = fmaf(e.x, r8, base0);
            a = fmaf(e.z, r10p, a);
            a = fmaf(e.y, r9m, a);
            S0 += fmaxf(a, 0.0f);
        }
        totE += nE;
        // no barrier here: round c+1's wtot write happens only after this
        // wave finished accumulating; elist writes only after barrier 1 of
        // round c+1, which all waves reach only after finishing this loop.
    }

    Sp[wave][lane] = (S0 + S1) + (S2 + S3);
    __syncthreads();

    // --- Phase 4: head, block-local ---
    const float valid = fmaxf((float)totE, 1.0f);
    const int h = tid;
    if (h < HID) {
        float s = 0.0f;
        #pragma unroll
        for (int w = 0; w < NWAVE; ++w) s += Sp[w][h];
        sb[h] = s;
    }
    __syncthreads();
    if (h < HID) {
        float acc0 = 0.0f, acc1 = 0.0f, acc2 = 0.0f, acc3 = 0.0f;
        #pragma unroll
        for (int k = 0; k < HID; k += 4) {
            acc0 = fmaf(sb[k],     W2[(k)     * HID + h], acc0);
            acc1 = fmaf(sb[k + 1], W2[(k + 1) * HID + h], acc1);
            acc2 = fmaf(sb[k + 2], W2[(k + 2) * HID + h], acc2);
            acc3 = fmaf(sb[k + 3], W2[(k + 3) * HID + h], acc3);
        }
        zz[h] = (acc0 + acc1 + acc2 + acc3) / valid + b2[h];
        if (h == 0) zz[HID] = valid / (float)MAX_EVENTS;
    }
    __syncthreads();
    if (h < HID) {
        float a0 = pb1[h], a1 = 0.0f, a2 = 0.0f, a3 = 0.0f;
        #pragma unroll
        for (int k = 0; k < HID; k += 4) {
            a0 = fmaf(zz[k],     P1[(k)     * HID + h], a0);
            a1 = fmaf(zz[k + 1], P1[(k + 1) * HID + h], a1);
            a2 = fmaf(zz[k + 2], P1[(k + 2) * HID + h], a2);
            a3 = fmaf(zz[k + 3], P1[(k + 3) * HID + h], a3);
        }
        a0 = fmaf(zz[HID], P1[HID * HID + h], a0);   // the valid/16384 row
        yy[h] = fmaxf((a0 + a1) + (a2 + a3), 0.0f);
    }
    __syncthreads();
    if (h < HID) {
        float o0 = pb2[h], o1 = 0.0f, o2 = 0.0f, o3 = 0.0f;
        #pragma unroll
        for (int k = 0; k < HID; k += 4) {
            o0 = fmaf(yy[k],     P2[(k)     * HID + h], o0);
            o1 = fmaf(yy[k + 1], P2[(k + 1) * HID + h], o1);
            o2 = fmaf(yy[k + 2], P2[(k + 2) * HID + h], o2);
            o3 = fmaf(yy[k + 3], P2[(k + 3) * HID + h], o3);
        }
        out[(size_t)b * OUT_DIM + h] = (o0 + o1) + (o2 + o3);
    }
}

extern "C" void kernel_launch(void* const* d_in, const int* in_sizes, int n_in,
                              void* d_out, int out_size, void* d_ws, size_t ws_size,
                              hipStream_t stream) {
    const float* x   = (const float*)d_in[0];
    const float* W1  = (const float*)d_in[1];
    const float* b1  = (const float*)d_in[2];
    const float* W2  = (const float*)d_in[3];
    const float* b2  = (const float*)d_in[4];
    const float* P1  = (const float*)d_in[5];
    const float* pb1 = (const float*)d_in[6];
    const float* P2  = (const float*)d_in[7];
    const float* pb2 = (const float*)d_in[8];
    float* out = (float*)d_out;

    fused_kernel<<<BATCH, 1024, 0, stream>>>(
        x, W1, b1, W2, b2, P1, pb1, P2, pb2, out);
}

// Round 8
// 17.085 us; speedup vs baseline: 3.0450x; 3.0450x over previous
//
#include <hip/hip_runtime.h>
#include <hip/hip_bf16.h>
#include <hip/hip_fp16.h>

#define T_LEN 2048
#define NCOMP 8
#define HID 64
#define OUT_DIM 64
#define BATCH 64
#define MAX_EVENTS (T_LEN * NCOMP)
#define NCHUNK 32              // 2048 / 64-bit chunks
#define PART_STRIDE 66         // 64 sums + count + pad
#define NWAVE 8                // 512-thread blocks

typedef unsigned long long u64;

// ws layout: [0, 64*8*66*4) : float partial[64][8][66]
#define PARTIAL_BYTES (64ULL * NCOMP * PART_STRIDE * 4)

// Pack two small ints (<=2048) as exact f16 pair in one uint.
static __device__ inline unsigned pack_f16pair(int a, int b) {
    __half ha = __float2half_rn((float)a);   // exact for |x| <= 2048
    __half hb = __float2half_rn((float)b);
    return (unsigned)__half_as_ushort(ha) | ((unsigned)__half_as_ushort(hb) << 16);
}

// ---------------------------------------------------------------------------
// Kernel 1: block per (b,c), 512 threads.
// R7 lesson: one ds_read_b128 per event (float4 events) costs ~12cy/event on
// the per-CU LDS pipe -> LDS-issue-bound. Fix: 4B/event (f16-packed t,nxt;
// EXACT since both are integers <= 2048) -> 4 events per b128 read.
// s-term eliminated: runs strictly alternate s, so s_i = s0 ^ (i&1) --
// the 4-unrolled loop statically picks baseEven/baseOdd (no per-event s).
// No device-scope fences/atomics (R4 lesson: ~35us).
// blockIdx = c*64 + b so the 8 readers of x[b] share blockIdx%8 -> same XCD L2.
// ---------------------------------------------------------------------------
__global__ __launch_bounds__(512) void event_kernel(
    const float* __restrict__ x,     // [B, T, C]
    const float* __restrict__ W1,    // [11, 64]
    const float* __restrict__ b1,    // [64]
    float* __restrict__ partial)     // [64][8][66]
{
    const int b    = blockIdx.x & 63;
    const int c    = blockIdx.x >> 6;
    const int tid  = threadIdx.x;
    const int lane = tid & 63;
    const int wave = tid >> 6;

    __shared__ u64 wsh[NCHUNK];          // raw bits of channel c
    __shared__ u64 tsh[NCHUNK];          // transition (run-start) masks
    __shared__ int nxtf[NCHUNK + 1];     // first transition in chunks >= k
    __shared__ int wtot[NWAVE];
    __shared__ unsigned elist[T_LEN];    // f16-packed events {t, nxt}
    __shared__ float Sp[NWAVE][HID];

    // --- Phase 1: coalesced load + ballot channel c ---
    const float4* xp = (const float4*)(x + ((size_t)b * T_LEN) * NCOMP);
    #pragma unroll
    for (int i = 0; i < 4; ++i) {
        int t = i * 512 + tid;
        float4 v0 = xp[t * 2];
        float4 v1 = xp[t * 2 + 1];
        unsigned m = 0;
        m |= (v0.x > 0.5f) ? 1u   : 0u;
        m |= (v0.y > 0.5f) ? 2u   : 0u;
        m |= (v0.z > 0.5f) ? 4u   : 0u;
        m |= (v0.w > 0.5f) ? 8u   : 0u;
        m |= (v1.x > 0.5f) ? 16u  : 0u;
        m |= (v1.y > 0.5f) ? 32u  : 0u;
        m |= (v1.z > 0.5f) ? 64u  : 0u;
        m |= (v1.w > 0.5f) ? 128u : 0u;
        u64 wd = __ballot((m >> c) & 1u);
        if (lane == 0) wsh[i * 8 + wave] = wd;   // chunk = i*8 + wave
    }
    __syncthreads();

    // --- Phase 2: transition masks + suffix-min of first-transition ---
    if (tid < NCHUNK) {
        u64 w = wsh[tid];
        u64 carry = (tid > 0) ? (wsh[tid - 1] >> 63) : 0ULL;
        u64 tr = w ^ ((w << 1) | carry);
        if (tid == 0) tr |= 1ULL;                // t=0 always a start
        tsh[tid] = tr;
        int first = tr ? tid * 64 + (__ffsll((long long)tr) - 1) : T_LEN;
        #pragma unroll
        for (int off = 1; off < NCHUNK; off <<= 1) {
            int v = __shfl_down(first, off);
            if (tid + off < NCHUNK) first = (v < first) ? v : first;
        }
        nxtf[tid] = first;
        if (tid == 0) nxtf[NCHUNK] = T_LEN;
    }
    __syncthreads();

    const int s0 = (int)(wsh[0] & 1ULL);         // s of first run (event 0)

    // --- Phase 3: per-nibble parallel decode -> compact f16-packed list ---
    const int ch = tid >> 4;                 // 16 threads per chunk
    const int sh = (tid & 15) * 4;           // bit offset of nibble
    const u64 full = tsh[ch];
    unsigned tr4 = (unsigned)((full >> sh) & 0xFu);
    int nt = __popc(tr4);

    int incl = nt;
    #pragma unroll
    for (int o = 1; o < 64; o <<= 1) {
        int v = __shfl_up(incl, o);
        if (lane >= o) incl += v;
    }
    if (lane == 63) wtot[wave] = incl;
    __syncthreads();
    int waveoff = 0;
    for (int w = 0; w < wave; ++w) waveoff += wtot[w];
    int nE = 0;
    #pragma unroll
    for (int w = 0; w < NWAVE; ++w) nE += wtot[w];
    int off = waveoff + incl - nt;

    unsigned rem = tr4;
    while (rem) {
        int p = __ffs(rem) - 1;
        rem &= rem - 1;
        int t = (tid << 2) + p;
        int nxt;
        if (rem) {
            nxt = (tid << 2) + __ffs(rem) - 1;
        } else {
            int bp = sh + 4;
            u64 above = (bp >= 64) ? 0ULL : (full & (~0ULL << bp));
            nxt = above ? ch * 64 + (__ffsll((long long)above) - 1) : nxtf[ch + 1];
        }
        elist[off++] = pack_f16pair(t, nxt);
    }
    __syncthreads();

    // --- Phase 4: accumulate; 4 events per ds_read_b128, alternating bases ---
    const float r8    = W1[8 * HID + lane];
    const float r9p   = W1[9 * HID + lane] * (1.0f / 2047.0f);
    const float r10p  = W1[10 * HID + lane] * (1.0f / 2048.0f);
    const float r9m   = r9p - r10p;                  // coeff of t
    const float base0 = W1[c * HID + lane] + b1[lane];
    const float base1 = base0 + r8;
    const float baseEven = s0 ? base1 : base0;       // events with even index
    const float baseOdd  = s0 ? base0 : base1;

    const int span = ((nE + 31) >> 5) << 2;          // ceil(nE/8), mult of 4
    const int i0   = wave * span;                    // multiple of 4 (even)
    const int i1   = (i0 + span < nE) ? (i0 + span) : nE;

    float S0 = 0.0f, S1 = 0.0f, S2 = 0.0f, S3 = 0.0f;
    int i = i0;
    for (; i + 3 < i1; i += 4) {
        uint4 e = *(const uint4*)&elist[i];          // 4 events, one b128
        __half2 h0 = *reinterpret_cast<__half2*>(&e.x);
        __half2 h1 = *reinterpret_cast<__half2*>(&e.y);
        __half2 h2 = *reinterpret_cast<__half2*>(&e.z);
        __half2 h3 = *reinterpret_cast<__half2*>(&e.w);
        float a0 = fmaf(__high2float(h0), r10p, baseEven);
        float a1 = fmaf(__high2float(h1), r10p, baseOdd);
        float a2 = fmaf(__high2float(h2), r10p, baseEven);
        float a3 = fmaf(__high2float(h3), r10p, baseOdd);
        a0 = fmaf(__low2float(h0), r9m, a0);
        a1 = fmaf(__low2float(h1), r9m, a1);
        a2 = fmaf(__low2float(h2), r9m, a2);
        a3 = fmaf(__low2float(h3), r9m, a3);
        S0 += fmaxf(a0, 0.0f);
        S1 += fmaxf(a1, 0.0f);
        S2 += fmaxf(a2, 0.0f);
        S3 += fmaxf(a3, 0.0f);
    }
    for (; i < i1; ++i) {
        unsigned eu = elist[i];
        __half2 h = *reinterpret_cast<__half2*>(&eu);
        float base = (i & 1) ? baseOdd : baseEven;
        float a = fmaf(__high2float(h), r10p, base);
        a = fmaf(__low2float(h), r9m, a);
        S0 += fmaxf(a, 0.0f);
    }
    Sp[wave][lane] = (S0 + S1) + (S2 + S3);
    __syncthreads();

    // --- Phase 5: plain partial store ---
    float* pp = partial + ((size_t)b * NCOMP + c) * PART_STRIDE;
    if (tid < HID) {
        float s = 0.0f;
        #pragma unroll
        for (int w = 0; w < NWAVE; ++w) s += Sp[w][tid];
        pp[tid] = s;
    }
    if (tid == HID) pp[HID] = (float)nE;
}

// ---------------------------------------------------------------------------
// Kernel 2: head. pooled = (S @ W2)/valid + b2; z = [pooled, valid/16384];
// out = relu(z @ P1 + pb1) @ P2 + pb2.
// ---------------------------------------------------------------------------
__global__ __launch_bounds__(64) void head_kernel(
    const float* __restrict__ partial,  // [64][8][66]
    const float* __restrict__ W2,
    const float* __restrict__ b2,
    const float* __restrict__ P1,
    const float* __restrict__ pb1,
    const float* __restrict__ P2,
    const float* __restrict__ pb2,
    float* __restrict__ out)
{
    const int b = blockIdx.x;
    const int h = threadIdx.x;

    __shared__ float sb[HID];
    __shared__ float z[HID + 1];
    __shared__ float y[HID];

    float s = 0.0f, cnt = 0.0f;
    #pragma unroll
    for (int cc = 0; cc < NCOMP; ++cc) {
        const float* pp = partial + ((size_t)b * NCOMP + cc) * PART_STRIDE;
        s   += pp[h];
        cnt += pp[HID];
    }
    float valid = fmaxf(cnt, 1.0f);
    sb[h] = s;
    __syncthreads();

    float acc = 0.0f;
    #pragma unroll
    for (int k = 0; k < HID; ++k) acc = fmaf(sb[k], W2[k * HID + h], acc);
    z[h] = acc / valid + b2[h];
    if (h == 0) z[HID] = valid / (float)MAX_EVENTS;
    __syncthreads();

    float a1 = pb1[h];
    #pragma unroll
    for (int k = 0; k < HID + 1; ++k) a1 = fmaf(z[k], P1[k * HID + h], a1);
    y[h] = fmaxf(a1, 0.0f);
    __syncthreads();

    float o = pb2[h];
    #pragma unroll
    for (int k = 0; k < HID; ++k) o = fmaf(y[k], P2[k * HID + h], o);
    out[(size_t)b * OUT_DIM + h] = o;
}

extern "C" void kernel_launch(void* const* d_in, const int* in_sizes, int n_in,
                              void* d_out, int out_size, void* d_ws, size_t ws_size,
                              hipStream_t stream) {
    const float* x   = (const float*)d_in[0];
    const float* W1  = (const float*)d_in[1];
    const float* b1  = (const float*)d_in[2];
    const float* W2  = (const float*)d_in[3];
    const float* b2  = (const float*)d_in[4];
    const float* P1  = (const float*)d_in[5];
    const float* pb1 = (const float*)d_in[6];
    const float* P2  = (const float*)d_in[7];
    const float* pb2 = (const float*)d_in[8];
    float* out = (float*)d_out;

    float* partial = (float*)d_ws;

    event_kernel<<<BATCH * NCOMP, 512, 0, stream>>>(x, W1, b1, partial);
    head_kernel<<<BATCH, 64, 0, stream>>>(partial, W2, b2, P1, pb1, P2, pb2, out);
}

// Round 9
// 16.237 us; speedup vs baseline: 3.2041x; 1.0522x over previous
//
#include <hip/hip_runtime.h>
#include <hip/hip_bf16.h>
#include <hip/hip_fp16.h>

#define T_LEN 2048
#define NCOMP 8
#define HID 64
#define OUT_DIM 64
#define BATCH 64
#define MAX_EVENTS (T_LEN * NCOMP)
#define NCHUNK 32              // 2048 / 64-bit chunks
#define PART_STRIDE 66         // 64 sums + count + pad
#define NWAVE 8                // 512-thread blocks

typedef unsigned long long u64;

// ws layout: [0, 64*8*66*4) : float partial[64][8][66]
#define PARTIAL_BYTES (64ULL * NCOMP * PART_STRIDE * 4)

// Pack two small ints (<=2048) as exact f16 pair in one uint.
static __device__ inline unsigned pack_f16pair(int a, int b) {
    __half ha = __float2half_rn((float)a);   // exact for |x| <= 2048
    __half hb = __float2half_rn((float)b);
    return (unsigned)__half_as_ushort(ha) | ((unsigned)__half_as_ushort(hb) << 16);
}

// ---------------------------------------------------------------------------
// Kernel 1: block per (b,c), 512 threads.
// R8 lesson: wave-uniform ds_read_b128 still costs ~12cy of the CU-shared LDS
// pipe. R9: lane-split accumulate -- each wave = 16 dim-groups x 4 event
// slices, so one uint4 read feeds 4 lanes' slices (LDS reads per wave drop
// 4x, interleaved 16B apart -> conflict-free) and the 2 f16 cvts amortize
// over 4 dims. Slice partials reduced with 2 shfl_xor butterflies.
// s-term via run alternation: s_i = s0 ^ (i&1), static in the 4-unroll.
// No device-scope fences/atomics (R4 lesson: ~35us).
// blockIdx = c*64 + b so the 8 readers of x[b] share blockIdx%8 -> same XCD L2.
// ---------------------------------------------------------------------------
__global__ __launch_bounds__(512) void event_kernel(
    const float* __restrict__ x,     // [B, T, C]
    const float* __restrict__ W1,    // [11, 64]
    const float* __restrict__ b1,    // [64]
    float* __restrict__ partial)     // [64][8][66]
{
    const int b    = blockIdx.x & 63;
    const int c    = blockIdx.x >> 6;
    const int tid  = threadIdx.x;
    const int lane = tid & 63;
    const int wave = tid >> 6;

    __shared__ u64 wsh[NCHUNK];          // raw bits of channel c
    __shared__ u64 tsh[NCHUNK];          // transition (run-start) masks
    __shared__ int nxtf[NCHUNK + 1];     // first transition in chunks >= k
    __shared__ int wtot[NWAVE];
    __shared__ unsigned elist[T_LEN];    // f16-packed events {t, nxt}
    __shared__ float Sp[NWAVE][HID];

    // --- Phase 1: coalesced load + ballot channel c ---
    const float4* xp = (const float4*)(x + ((size_t)b * T_LEN) * NCOMP);
    #pragma unroll
    for (int i = 0; i < 4; ++i) {
        int t = i * 512 + tid;
        float4 v0 = xp[t * 2];
        float4 v1 = xp[t * 2 + 1];
        unsigned m = 0;
        m |= (v0.x > 0.5f) ? 1u   : 0u;
        m |= (v0.y > 0.5f) ? 2u   : 0u;
        m |= (v0.z > 0.5f) ? 4u   : 0u;
        m |= (v0.w > 0.5f) ? 8u   : 0u;
        m |= (v1.x > 0.5f) ? 16u  : 0u;
        m |= (v1.y > 0.5f) ? 32u  : 0u;
        m |= (v1.z > 0.5f) ? 64u  : 0u;
        m |= (v1.w > 0.5f) ? 128u : 0u;
        u64 wd = __ballot((m >> c) & 1u);
        if (lane == 0) wsh[i * 8 + wave] = wd;   // chunk = i*8 + wave
    }
    __syncthreads();

    // --- Phase 2: transition masks + suffix-min of first-transition ---
    if (tid < NCHUNK) {
        u64 w = wsh[tid];
        u64 carry = (tid > 0) ? (wsh[tid - 1] >> 63) : 0ULL;
        u64 tr = w ^ ((w << 1) | carry);
        if (tid == 0) tr |= 1ULL;                // t=0 always a start
        tsh[tid] = tr;
        int first = tr ? tid * 64 + (__ffsll((long long)tr) - 1) : T_LEN;
        #pragma unroll
        for (int off = 1; off < NCHUNK; off <<= 1) {
            int v = __shfl_down(first, off);
            if (tid + off < NCHUNK) first = (v < first) ? v : first;
        }
        nxtf[tid] = first;
        if (tid == 0) nxtf[NCHUNK] = T_LEN;
    }
    __syncthreads();

    const int s0 = (int)(wsh[0] & 1ULL);         // s of first run (event 0)

    // --- Phase 3: per-nibble parallel decode -> compact f16-packed list ---
    const int ch = tid >> 4;                 // 16 threads per chunk
    const int sh = (tid & 15) * 4;           // bit offset of nibble
    const u64 full = tsh[ch];
    unsigned tr4 = (unsigned)((full >> sh) & 0xFu);
    int nt = __popc(tr4);

    int incl = nt;
    #pragma unroll
    for (int o = 1; o < 64; o <<= 1) {
        int v = __shfl_up(incl, o);
        if (lane >= o) incl += v;
    }
    if (lane == 63) wtot[wave] = incl;
    __syncthreads();
    int waveoff = 0;
    for (int w = 0; w < wave; ++w) waveoff += wtot[w];
    int nE = 0;
    #pragma unroll
    for (int w = 0; w < NWAVE; ++w) nE += wtot[w];
    int off = waveoff + incl - nt;

    unsigned rem = tr4;
    while (rem) {
        int p = __ffs(rem) - 1;
        rem &= rem - 1;
        int t = (tid << 2) + p;
        int nxt;
        if (rem) {
            nxt = (tid << 2) + __ffs(rem) - 1;
        } else {
            int bp = sh + 4;
            u64 above = (bp >= 64) ? 0ULL : (full & (~0ULL << bp));
            nxt = above ? ch * 64 + (__ffsll((long long)above) - 1) : nxtf[ch + 1];
        }
        elist[off++] = pack_f16pair(t, nxt);
    }
    __syncthreads();

    // --- Phase 4: lane-split accumulate ---
    // lane = (eg, dg): eg = lane>>4 event-slice, dg = lane&15 -> dims 4dg..4dg+3
    const int dg = lane & 15;
    const int eg = lane >> 4;

    const float4 w9  = *(const float4*)&W1[9 * HID + 4 * dg];
    const float4 w10 = *(const float4*)&W1[10 * HID + 4 * dg];
    const float4 w8  = *(const float4*)&W1[8 * HID + 4 * dg];
    const float4 wc  = *(const float4*)&W1[c * HID + 4 * dg];
    const float4 bb  = *(const float4*)&b1[4 * dg];

    const float r10p0 = w10.x * (1.0f / 2048.0f);
    const float r10p1 = w10.y * (1.0f / 2048.0f);
    const float r10p2 = w10.z * (1.0f / 2048.0f);
    const float r10p3 = w10.w * (1.0f / 2048.0f);
    const float r9m0  = w9.x * (1.0f / 2047.0f) - r10p0;
    const float r9m1  = w9.y * (1.0f / 2047.0f) - r10p1;
    const float r9m2  = w9.z * (1.0f / 2047.0f) - r10p2;
    const float r9m3  = w9.w * (1.0f / 2047.0f) - r10p3;
    const float b00 = wc.x + bb.x, b01 = wc.y + bb.y;
    const float b02 = wc.z + bb.z, b03 = wc.w + bb.w;
    const float b10 = b00 + w8.x, b11 = b01 + w8.y;
    const float b12 = b02 + w8.z, b13 = b03 + w8.w;
    const float beE0 = s0 ? b10 : b00, beO0 = s0 ? b00 : b10;
    const float beE1 = s0 ? b11 : b01, beO1 = s0 ? b01 : b11;
    const float beE2 = s0 ? b12 : b02, beO2 = s0 ? b02 : b12;
    const float beE3 = s0 ? b13 : b03, beO3 = s0 ? b03 : b13;

    // per-wave span, multiple of 16 so each eg-slice reads aligned uint4s
    const int span = ((nE + NWAVE * 16 - 1) >> 7) << 4;
    const int i0   = wave * span;
    const int i1   = (i0 + span < nE) ? (i0 + span) : nE;

    float S0 = 0.0f, S1 = 0.0f, S2 = 0.0f, S3 = 0.0f;

#define EV_ACC(tf, nf, BE)                                            \
    S0 += fmaxf(fmaf(tf, r9m0, fmaf(nf, r10p0, BE##0)), 0.0f);        \
    S1 += fmaxf(fmaf(tf, r9m1, fmaf(nf, r10p1, BE##1)), 0.0f);        \
    S2 += fmaxf(fmaf(tf, r9m2, fmaf(nf, r10p2, BE##2)), 0.0f);        \
    S3 += fmaxf(fmaf(tf, r9m3, fmaf(nf, r10p3, BE##3)), 0.0f);

    int i = i0 + 4 * eg;                         // even, 16B-aligned index
    for (; i + 3 < i1; i += 16) {                // interleaved slices
        uint4 e = *(const uint4*)&elist[i];
        __half2 h0 = *reinterpret_cast<const __half2*>(&e.x);
        __half2 h1 = *reinterpret_cast<const __half2*>(&e.y);
        __half2 h2 = *reinterpret_cast<const __half2*>(&e.z);
        __half2 h3 = *reinterpret_cast<const __half2*>(&e.w);
        float t0 = __low2float(h0), n0 = __high2float(h0);
        float t1 = __low2float(h1), n1 = __high2float(h1);
        float t2 = __low2float(h2), n2 = __high2float(h2);
        float t3 = __low2float(h3), n3 = __high2float(h3);
        EV_ACC(t0, n0, beE)
        EV_ACC(t1, n1, beO)
        EV_ACC(t2, n2, beE)
        EV_ACC(t3, n3, beO)
    }
    if (i < i1) {                                 // <=3 leftover events
        for (int ii = i; ii < i1 && ii < i + 4; ++ii) {
            unsigned eu = elist[ii];
            __half2 hh = *reinterpret_cast<const __half2*>(&eu);
            float tf = __low2float(hh), nf = __high2float(hh);
            const int odd = ii & 1;
            float B0 = odd ? beO0 : beE0, B1 = odd ? beO1 : beE1;
            float B2 = odd ? beO2 : beE2, B3 = odd ? beO3 : beE3;
            S0 += fmaxf(fmaf(tf, r9m0, fmaf(nf, r10p0, B0)), 0.0f);
            S1 += fmaxf(fmaf(tf, r9m1, fmaf(nf, r10p1, B1)), 0.0f);
            S2 += fmaxf(fmaf(tf, r9m2, fmaf(nf, r10p2, B2)), 0.0f);
            S3 += fmaxf(fmaf(tf, r9m3, fmaf(nf, r10p3, B3)), 0.0f);
        }
    }
#undef EV_ACC

    // butterfly over the 4 event-slices (eg = lane bits 4,5)
    S0 += __shfl_xor(S0, 16); S0 += __shfl_xor(S0, 32);
    S1 += __shfl_xor(S1, 16); S1 += __shfl_xor(S1, 32);
    S2 += __shfl_xor(S2, 16); S2 += __shfl_xor(S2, 32);
    S3 += __shfl_xor(S3, 16); S3 += __shfl_xor(S3, 32);
    if (eg == 0) {
        *(float4*)&Sp[wave][4 * dg] = make_float4(S0, S1, S2, S3);
    }
    __syncthreads();

    // --- Phase 5: plain partial store ---
    float* pp = partial + ((size_t)b * NCOMP + c) * PART_STRIDE;
    if (tid < HID) {
        float s = 0.0f;
        #pragma unroll
        for (int w = 0; w < NWAVE; ++w) s += Sp[w][tid];
        pp[tid] = s;
    }
    if (tid == HID) pp[HID] = (float)nE;
}

// ---------------------------------------------------------------------------
// Kernel 2: head, 256 threads: 4-way k-split per stage with LDS tree-reduce.
// pooled = (S @ W2)/valid + b2; z = [pooled, valid/16384];
// out = relu(z @ P1 + pb1) @ P2 + pb2.
// ---------------------------------------------------------------------------
__global__ __launch_bounds__(256) void head_kernel(
    const float* __restrict__ partial,  // [64][8][66]
    const float* __restrict__ W2,
    const float* __restrict__ b2,
    const float* __restrict__ P1,
    const float* __restrict__ pb1,
    const float* __restrict__ P2,
    const float* __restrict__ pb2,
    float* __restrict__ out)
{
    const int b   = blockIdx.x;
    const int tid = threadIdx.x;
    const int h   = tid & 63;
    const int q   = tid >> 6;            // k-quarter 0..3

    __shared__ float red[4][HID];
    __shared__ float sb[HID];
    __shared__ float cnt8[8];
    __shared__ float z[HID + 1];
    __shared__ float y[HID];

    const float* pb_ = partial + (size_t)b * NCOMP * PART_STRIDE;

    // pooled partial sums: quarter q covers channels 2q, 2q+1
    red[q][h] = pb_[(2 * q) * PART_STRIDE + h] + pb_[(2 * q + 1) * PART_STRIDE + h];
    if (tid < NCOMP) cnt8[tid] = pb_[tid * PART_STRIDE + HID];
    __syncthreads();
    if (q == 0) sb[h] = red[0][h] + red[1][h] + red[2][h] + red[3][h];
    __syncthreads();
    const float valid = fmaxf(cnt8[0] + cnt8[1] + cnt8[2] + cnt8[3] +
                              cnt8[4] + cnt8[5] + cnt8[6] + cnt8[7], 1.0f);

    // W2 stage
    float acc = 0.0f;
    #pragma unroll
    for (int k = 16 * q; k < 16 * q + 16; ++k)
        acc = fmaf(sb[k], W2[k * HID + h], acc);
    red[q][h] = acc;
    __syncthreads();
    if (q == 0) z[h] = (red[0][h] + red[1][h] + red[2][h] + red[3][h]) / valid + b2[h];
    if (tid == 0) z[HID] = valid / (float)MAX_EVENTS;
    __syncthreads();

    // P1 stage (65 rows; row 64 handled by q==0)
    float a = (q == 0) ? fmaf(z[HID], P1[HID * HID + h], pb1[h]) : 0.0f;
    #pragma unroll
    for (int k = 16 * q; k < 16 * q + 16; ++k)
        a = fmaf(z[k], P1[k * HID + h], a);
    red[q][h] = a;
    __syncthreads();
    if (q == 0) y[h] = fmaxf(red[0][h] + red[1][h] + red[2][h] + red[3][h], 0.0f);
    __syncthreads();

    // P2 stage
    float o = (q == 0) ? pb2[h] : 0.0f;
    #pragma unroll
    for (int k = 16 * q; k < 16 * q + 16; ++k)
        o = fmaf(y[k], P2[k * HID + h], o);
    red[q][h] = o;
    __syncthreads();
    if (q == 0) out[(size_t)b * OUT_DIM + h] = red[0][h] + red[1][h] + red[2][h] + red[3][h];
}

extern "C" void kernel_launch(void* const* d_in, const int* in_sizes, int n_in,
                              void* d_out, int out_size, void* d_ws, size_t ws_size,
                              hipStream_t stream) {
    const float* x   = (const float*)d_in[0];
    const float* W1  = (const float*)d_in[1];
    const float* b1  = (const float*)d_in[2];
    const float* W2  = (const float*)d_in[3];
    const float* b2  = (const float*)d_in[4];
    const float* P1  = (const float*)d_in[5];
    const float* pb1 = (const float*)d_in[6];
    const float* P2  = (const float*)d_in[7];
    const float* pb2 = (const float*)d_in[8];
    float* out = (float*)d_out;

    float* partial = (float*)d_ws;

    event_kernel<<<BATCH * NCOMP, 512, 0, stream>>>(x, W1, b1, partial);
    head_kernel<<<BATCH, 256, 0, stream>>>(partial, W2, b2, P1, pb1, P2, pb2, out);
}

// Round 10
// 16.101 us; speedup vs baseline: 3.2311x; 1.0084x over previous
//
#include <hip/hip_runtime.h>
#include <hip/hip_bf16.h>
#include <hip/hip_fp16.h>

#define T_LEN 2048
#define NCOMP 8
#define HID 64
#define OUT_DIM 64
#define BATCH 64
#define MAX_EVENTS (T_LEN * NCOMP)
#define NCHUNK 32              // 2048 / 64-bit chunks
#define PART_STRIDE 66         // 64 sums + count + pad
#define NWAVE 8                // 512-thread blocks

typedef unsigned long long u64;

// ws layout: [0, 64*8*66*4) : float partial[64][8][66]
#define PARTIAL_BYTES (64ULL * NCOMP * PART_STRIDE * 4)

// Pack two small ints (<=2048) as exact f16 pair in one uint.
static __device__ inline unsigned pack_f16pair(int a, int b) {
    __half ha = __float2half_rn((float)a);   // exact for |x| <= 2048
    __half hb = __float2half_rn((float)b);
    return (unsigned)__half_as_ushort(ha) | ((unsigned)__half_as_ushort(hb) << 16);
}

// ---------------------------------------------------------------------------
// Kernel 1: block per (b,c), 512 threads.
// Structure proven over R5-R9: coalesced ballot load -> transition masks ->
// per-nibble parallel decode into f16-packed 4B events (exact) -> lane-split
// accumulate (wave = 16 dim-groups x 4 event-slices; one uint4 feeds 4 lanes'
// slices; s-term via run alternation s_i = s0^(i&1)) -> shfl_xor reduce ->
// plain partial store. R10: accumulate unrolled x2 (32 events/iter, dual
// accumulator sets) to halve loop overhead and deepen independent FMA chains.
// No device-scope fences/atomics (R4 lesson: ~35us).
// blockIdx = c*64 + b so the 8 readers of x[b] share blockIdx%8 -> same XCD L2.
// ---------------------------------------------------------------------------
__global__ __launch_bounds__(512) void event_kernel(
    const float* __restrict__ x,     // [B, T, C]
    const float* __restrict__ W1,    // [11, 64]
    const float* __restrict__ b1,    // [64]
    float* __restrict__ partial)     // [64][8][66]
{
    const int b    = blockIdx.x & 63;
    const int c    = blockIdx.x >> 6;
    const int tid  = threadIdx.x;
    const int lane = tid & 63;
    const int wave = tid >> 6;

    __shared__ u64 wsh[NCHUNK];          // raw bits of channel c
    __shared__ u64 tsh[NCHUNK];          // transition (run-start) masks
    __shared__ int nxtf[NCHUNK + 1];     // first transition in chunks >= k
    __shared__ int wtot[NWAVE];
    __shared__ unsigned elist[T_LEN];    // f16-packed events {t, nxt}
    __shared__ float Sp[NWAVE][HID];

    // --- Phase 1: coalesced load + ballot channel c ---
    const float4* xp = (const float4*)(x + ((size_t)b * T_LEN) * NCOMP);
    #pragma unroll
    for (int i = 0; i < 4; ++i) {
        int t = i * 512 + tid;
        float4 v0 = xp[t * 2];
        float4 v1 = xp[t * 2 + 1];
        unsigned m = 0;
        m |= (v0.x > 0.5f) ? 1u   : 0u;
        m |= (v0.y > 0.5f) ? 2u   : 0u;
        m |= (v0.z > 0.5f) ? 4u   : 0u;
        m |= (v0.w > 0.5f) ? 8u   : 0u;
        m |= (v1.x > 0.5f) ? 16u  : 0u;
        m |= (v1.y > 0.5f) ? 32u  : 0u;
        m |= (v1.z > 0.5f) ? 64u  : 0u;
        m |= (v1.w > 0.5f) ? 128u : 0u;
        u64 wd = __ballot((m >> c) & 1u);
        if (lane == 0) wsh[i * 8 + wave] = wd;   // chunk = i*8 + wave
    }
    __syncthreads();

    // --- Phase 2: transition masks + suffix-min of first-transition ---
    if (tid < NCHUNK) {
        u64 w = wsh[tid];
        u64 carry = (tid > 0) ? (wsh[tid - 1] >> 63) : 0ULL;
        u64 tr = w ^ ((w << 1) | carry);
        if (tid == 0) tr |= 1ULL;                // t=0 always a start
        tsh[tid] = tr;
        int first = tr ? tid * 64 + (__ffsll((long long)tr) - 1) : T_LEN;
        #pragma unroll
        for (int off = 1; off < NCHUNK; off <<= 1) {
            int v = __shfl_down(first, off);
            if (tid + off < NCHUNK) first = (v < first) ? v : first;
        }
        nxtf[tid] = first;
        if (tid == 0) nxtf[NCHUNK] = T_LEN;
    }
    __syncthreads();

    const int s0 = (int)(wsh[0] & 1ULL);         // s of first run (event 0)

    // --- Phase 3: per-nibble parallel decode -> compact f16-packed list ---
    const int ch = tid >> 4;                 // 16 threads per chunk
    const int sh = (tid & 15) * 4;           // bit offset of nibble
    const u64 full = tsh[ch];
    unsigned tr4 = (unsigned)((full >> sh) & 0xFu);
    int nt = __popc(tr4);

    int incl = nt;
    #pragma unroll
    for (int o = 1; o < 64; o <<= 1) {
        int v = __shfl_up(incl, o);
        if (lane >= o) incl += v;
    }
    if (lane == 63) wtot[wave] = incl;
    __syncthreads();
    int waveoff = 0;
    for (int w = 0; w < wave; ++w) waveoff += wtot[w];
    int nE = 0;
    #pragma unroll
    for (int w = 0; w < NWAVE; ++w) nE += wtot[w];
    int off = waveoff + incl - nt;

    unsigned rem = tr4;
    while (rem) {
        int p = __ffs(rem) - 1;
        rem &= rem - 1;
        int t = (tid << 2) + p;
        int nxt;
        if (rem) {
            nxt = (tid << 2) + __ffs(rem) - 1;
        } else {
            int bp = sh + 4;
            u64 above = (bp >= 64) ? 0ULL : (full & (~0ULL << bp));
            nxt = above ? ch * 64 + (__ffsll((long long)above) - 1) : nxtf[ch + 1];
        }
        elist[off++] = pack_f16pair(t, nxt);
    }
    __syncthreads();

    // --- Phase 4: lane-split accumulate, x2 unrolled ---
    // lane = (eg, dg): eg = lane>>4 event-slice, dg = lane&15 -> dims 4dg..4dg+3
    const int dg = lane & 15;
    const int eg = lane >> 4;

    const float4 w9  = *(const float4*)&W1[9 * HID + 4 * dg];
    const float4 w10 = *(const float4*)&W1[10 * HID + 4 * dg];
    const float4 w8  = *(const float4*)&W1[8 * HID + 4 * dg];
    const float4 wc  = *(const float4*)&W1[c * HID + 4 * dg];
    const float4 bb  = *(const float4*)&b1[4 * dg];

    const float r10p0 = w10.x * (1.0f / 2048.0f);
    const float r10p1 = w10.y * (1.0f / 2048.0f);
    const float r10p2 = w10.z * (1.0f / 2048.0f);
    const float r10p3 = w10.w * (1.0f / 2048.0f);
    const float r9m0  = w9.x * (1.0f / 2047.0f) - r10p0;
    const float r9m1  = w9.y * (1.0f / 2047.0f) - r10p1;
    const float r9m2  = w9.z * (1.0f / 2047.0f) - r10p2;
    const float r9m3  = w9.w * (1.0f / 2047.0f) - r10p3;
    const float b00 = wc.x + bb.x, b01 = wc.y + bb.y;
    const float b02 = wc.z + bb.z, b03 = wc.w + bb.w;
    const float b10 = b00 + w8.x, b11 = b01 + w8.y;
    const float b12 = b02 + w8.z, b13 = b03 + w8.w;
    const float beE0 = s0 ? b10 : b00, beO0 = s0 ? b00 : b10;
    const float beE1 = s0 ? b11 : b01, beO1 = s0 ? b01 : b11;
    const float beE2 = s0 ? b12 : b02, beO2 = s0 ? b02 : b12;
    const float beE3 = s0 ? b13 : b03, beO3 = s0 ? b03 : b13;

    // per-wave span, multiple of 16 so each eg-slice reads aligned uint4s
    const int span = ((nE + NWAVE * 16 - 1) >> 7) << 4;
    const int i0   = wave * span;
    const int i1   = (i0 + span < nE) ? (i0 + span) : nE;

    float S0 = 0.0f, S1 = 0.0f, S2 = 0.0f, S3 = 0.0f;
    float T0 = 0.0f, T1 = 0.0f, T2 = 0.0f, T3 = 0.0f;

#define EV_ACC4(A0, A1, A2, A3, tf, nf, BE)                            \
    A0 += fmaxf(fmaf(tf, r9m0, fmaf(nf, r10p0, BE##0)), 0.0f);         \
    A1 += fmaxf(fmaf(tf, r9m1, fmaf(nf, r10p1, BE##1)), 0.0f);         \
    A2 += fmaxf(fmaf(tf, r9m2, fmaf(nf, r10p2, BE##2)), 0.0f);         \
    A3 += fmaxf(fmaf(tf, r9m3, fmaf(nf, r10p3, BE##3)), 0.0f);

#define EV_UNPACK(e, hvar, tvar, nvar)                                 \
    __half2 hvar = *reinterpret_cast<const __half2*>(&(e));            \
    float tvar = __low2float(hvar), nvar = __high2float(hvar);

    int i = i0 + 4 * eg;                         // even, 16B-aligned index
    for (; i + 19 < i1; i += 32) {               // x2: two uint4s per iter
        uint4 ea = *(const uint4*)&elist[i];
        uint4 eb = *(const uint4*)&elist[i + 16];
        EV_UNPACK(ea.x, ha0, ta0, na0)
        EV_UNPACK(ea.y, ha1, ta1, na1)
        EV_UNPACK(ea.z, ha2, ta2, na2)
        EV_UNPACK(ea.w, ha3, ta3, na3)
        EV_UNPACK(eb.x, hb0, tb0, nb0)
        EV_UNPACK(eb.y, hb1, tb1, nb1)
        EV_UNPACK(eb.z, hb2, tb2, nb2)
        EV_UNPACK(eb.w, hb3, tb3, nb3)
        EV_ACC4(S0, S1, S2, S3, ta0, na0, beE)
        EV_ACC4(S0, S1, S2, S3, ta1, na1, beO)
        EV_ACC4(S0, S1, S2, S3, ta2, na2, beE)
        EV_ACC4(S0, S1, S2, S3, ta3, na3, beO)
        EV_ACC4(T0, T1, T2, T3, tb0, nb0, beE)
        EV_ACC4(T0, T1, T2, T3, tb1, nb1, beO)
        EV_ACC4(T0, T1, T2, T3, tb2, nb2, beE)
        EV_ACC4(T0, T1, T2, T3, tb3, nb3, beO)
    }
    for (; i + 3 < i1; i += 16) {                // single uint4 per iter
        uint4 e = *(const uint4*)&elist[i];
        EV_UNPACK(e.x, h0, t0, n0)
        EV_UNPACK(e.y, h1, t1, n1)
        EV_UNPACK(e.z, h2, t2, n2)
        EV_UNPACK(e.w, h3, t3, n3)
        EV_ACC4(S0, S1, S2, S3, t0, n0, beE)
        EV_ACC4(S0, S1, S2, S3, t1, n1, beO)
        EV_ACC4(S0, S1, S2, S3, t2, n2, beE)
        EV_ACC4(S0, S1, S2, S3, t3, n3, beO)
    }
    if (i < i1) {                                 // <=3 leftover events
        for (int ii = i; ii < i1 && ii < i + 4; ++ii) {
            unsigned eu = elist[ii];
            __half2 hh = *reinterpret_cast<const __half2*>(&eu);
            float tf = __low2float(hh), nf = __high2float(hh);
            const int odd = ii & 1;
            float B0 = odd ? beO0 : beE0, B1 = odd ? beO1 : beE1;
            float B2 = odd ? beO2 : beE2, B3 = odd ? beO3 : beE3;
            S0 += fmaxf(fmaf(tf, r9m0, fmaf(nf, r10p0, B0)), 0.0f);
            S1 += fmaxf(fmaf(tf, r9m1, fmaf(nf, r10p1, B1)), 0.0f);
            S2 += fmaxf(fmaf(tf, r9m2, fmaf(nf, r10p2, B2)), 0.0f);
            S3 += fmaxf(fmaf(tf, r9m3, fmaf(nf, r10p3, B3)), 0.0f);
        }
    }
#undef EV_ACC4
#undef EV_UNPACK
    S0 += T0; S1 += T1; S2 += T2; S3 += T3;

    // butterfly over the 4 event-slices (eg = lane bits 4,5)
    S0 += __shfl_xor(S0, 16); S0 += __shfl_xor(S0, 32);
    S1 += __shfl_xor(S1, 16); S1 += __shfl_xor(S1, 32);
    S2 += __shfl_xor(S2, 16); S2 += __shfl_xor(S2, 32);
    S3 += __shfl_xor(S3, 16); S3 += __shfl_xor(S3, 32);
    if (eg == 0) {
        *(float4*)&Sp[wave][4 * dg] = make_float4(S0, S1, S2, S3);
    }
    __syncthreads();

    // --- Phase 5: plain partial store ---
    float* pp = partial + ((size_t)b * NCOMP + c) * PART_STRIDE;
    if (tid < HID) {
        float s = 0.0f;
        #pragma unroll
        for (int w = 0; w < NWAVE; ++w) s += Sp[w][tid];
        pp[tid] = s;
    }
    if (tid == HID) pp[HID] = (float)nE;
}

// ---------------------------------------------------------------------------
// Kernel 2: head, 256 threads, 4-way k-split. R10: ALL weight loads hoisted
// into registers (fully unrolled -> static indexing, no scratch) BEFORE the
// partial read, so a single HBM-latency window covers all three stages
// (previously three cold-load stalls between barriers). Summation order
// unchanged -> bitwise-identical output.
// ---------------------------------------------------------------------------
__global__ __launch_bounds__(256) void head_kernel(
    const float* __restrict__ partial,  // [64][8][66]
    const float* __restrict__ W2,
    const float* __restrict__ b2,
    const float* __restrict__ P1,
    const float* __restrict__ pb1,
    const float* __restrict__ P2,
    const float* __restrict__ pb2,
    float* __restrict__ out)
{
    const int b   = blockIdx.x;
    const int tid = threadIdx.x;
    const int h   = tid & 63;
    const int q   = tid >> 6;            // k-quarter 0..3

    __shared__ float red[4][HID];
    __shared__ float sb[HID];
    __shared__ float cnt8[8];
    __shared__ float z[HID + 1];
    __shared__ float y[HID];

    // --- preload all weights (independent of K1's output) ---
    float w2r[16], p1r[16], p2r[16];
    #pragma unroll
    for (int j = 0; j < 16; ++j) {
        const int k = 16 * q + j;
        w2r[j] = W2[k * HID + h];
        p1r[j] = P1[k * HID + h];
        p2r[j] = P2[k * HID + h];
    }
    const float p1x  = (q == 0) ? P1[HID * HID + h] : 0.0f;   // row 64
    const float b2h  = b2[h];
    const float pb1h = pb1[h];
    const float pb2h = pb2[h];

    const float* pb_ = partial + (size_t)b * NCOMP * PART_STRIDE;

    // pooled partial sums: quarter q covers channels 2q, 2q+1
    red[q][h] = pb_[(2 * q) * PART_STRIDE + h] + pb_[(2 * q + 1) * PART_STRIDE + h];
    if (tid < NCOMP) cnt8[tid] = pb_[tid * PART_STRIDE + HID];
    __syncthreads();
    if (q == 0) sb[h] = red[0][h] + red[1][h] + red[2][h] + red[3][h];
    __syncthreads();
    const float valid = fmaxf(cnt8[0] + cnt8[1] + cnt8[2] + cnt8[3] +
                              cnt8[4] + cnt8[5] + cnt8[6] + cnt8[7], 1.0f);

    // W2 stage
    float acc = 0.0f;
    #pragma unroll
    for (int j = 0; j < 16; ++j)
        acc = fmaf(sb[16 * q + j], w2r[j], acc);
    red[q][h] = acc;
    __syncthreads();
    if (q == 0) z[h] = (red[0][h] + red[1][h] + red[2][h] + red[3][h]) / valid + b2h;
    if (tid == 0) z[HID] = valid / (float)MAX_EVENTS;
    __syncthreads();

    // P1 stage (65 rows; row 64 handled by q==0)
    float a = (q == 0) ? fmaf(z[HID], p1x, pb1h) : 0.0f;
    #pragma unroll
    for (int j = 0; j < 16; ++j)
        a = fmaf(z[16 * q + j], p1r[j], a);
    red[q][h] = a;
    __syncthreads();
    if (q == 0) y[h] = fmaxf(red[0][h] + red[1][h] + red[2][h] + red[3][h], 0.0f);
    __syncthreads();

    // P2 stage
    float o = (q == 0) ? pb2h : 0.0f;
    #pragma unroll
    for (int j = 0; j < 16; ++j)
        o = fmaf(y[16 * q + j], p2r[j], o);
    red[q][h] = o;
    __syncthreads();
    if (q == 0) out[(size_t)b * OUT_DIM + h] = red[0][h] + red[1][h] + red[2][h] + red[3][h];
}

extern "C" void kernel_launch(void* const* d_in, const int* in_sizes, int n_in,
                              void* d_out, int out_size, void* d_ws, size_t ws_size,
                              hipStream_t stream) {
    const float* x   = (const float*)d_in[0];
    const float* W1  = (const float*)d_in[1];
    const float* b1  = (const float*)d_in[2];
    const float* W2  = (const float*)d_in[3];
    const float* b2  = (const float*)d_in[4];
    const float* P1  = (const float*)d_in[5];
    const float* pb1 = (const float*)d_in[6];
    const float* P2  = (const float*)d_in[7];
    const float* pb2 = (const float*)d_in[8];
    float* out = (float*)d_out;

    float* partial = (float*)d_ws;

    event_kernel<<<BATCH * NCOMP, 512, 0, stream>>>(x, W1, b1, partial);
    head_kernel<<<BATCH, 256, 0, stream>>>(partial, W2, b2, P1, pb1, P2, pb2, out);
}